// Round 13
// baseline (105.452 us; speedup 1.0000x reference)
//
#include <hip/hip_runtime.h>

// ---------------------------------------------------------------------------
// SPP_CNN: conv1d(128->128,K=21,VALID) + BN(eval) + LeakyReLU(0.01)
//          + 2x ragged SPP-max (levels 1,2) + FC(768->2)
// R13 = R12 + wave-staggered tap order in k_conv: wave wid processes taps
// (5*wid + kk) mod 21 (conv taps commute in exact i32), so co-resident
// waves' vmcnt/lgkmcnt stall points interleave instead of hitting in
// lockstep. No register/math change; output bit-identical to R12.
// Invariants (R3/R8/R10): wave = 64co x 128t, av 8KB/tap/wave, ~64-MFMA
// prefetch distance, 2 blocks/CU. Early-exit on t0 >= L1(b).
// Pipeline: 4 dispatches (absmax -> fused prep -> conv -> fc).
// Workspace layout:
//   Xt   : i8  [32][8192][128]  (x transposed, quantized)     @ 0
//   Wp   : i8  [21][2][8][64][16] ([k][wr][f=ks*4+m][lane][e])@ 33554432
//   bnA  : f32 [128] (gamma*inv/(sx*sw))                      @ 33898496
//   bnB  : f32 [128]                                          @ 33899008
//   feat : u32 [32][768]  (monotonic float keys)              @ 33899520
//   parts: f32 [1344]     (absmax per-wave partials)          @ 33997824
// ---------------------------------------------------------------------------

typedef __attribute__((ext_vector_type(4))) float f32x4;
typedef __attribute__((ext_vector_type(4))) int i32x4;
typedef unsigned short u16;
typedef unsigned int u32;
typedef signed char i8;

#define T_SZ 8192
#define C_SZ 128
#define B_SZ 32
#define KW 21
#define FEAT 768
#define SX 25.4f              /* 127/5: x ~ N(0,1), clip at 5 sigma */
#define IMIN (-2147483647 - 1)

#define XT_OFF  0
#define WP_OFF  33554432u
#define BNA_OFF 33898496u
#define BNB_OFF 33899008u
#define FK_OFF  33899520u
#define PT_OFF  33997824u

__device__ __forceinline__ u32 fkey(float f) {          // order-preserving
  u32 u = __float_as_uint(f);
  return (u & 0x80000000u) ? ~u : (u | 0x80000000u);
}
__device__ __forceinline__ float funkey(u32 k) {
  u32 u = (k & 0x80000000u) ? (k ^ 0x80000000u) : ~k;
  return __uint_as_float(u);
}

__device__ __forceinline__ i8 q8(float v) {
  v = fminf(fmaxf(v, -127.f), 127.f);
  return (i8)__float2int_rn(v);
}

__device__ __forceinline__ void gload_lds16(void* lds, const void* g) {
  __builtin_amdgcn_global_load_lds(
      (const __attribute__((address_space(1))) u32*)g,
      (__attribute__((address_space(3))) u32*)lds, 16, 0, 0);
}

// --------------------------- prep: |W| absmax partials ---------------------
__global__ void k_absmax(const float* __restrict__ W, float* __restrict__ parts) {
  const int i0 = ((int)blockIdx.x * 256 + (int)threadIdx.x) * 4;  // 336 blocks
  float m = 0.f;
#pragma unroll
  for (int j = 0; j < 4; ++j) m = fmaxf(m, fabsf(W[i0 + j]));
#pragma unroll
  for (int d = 1; d < 64; d <<= 1) m = fmaxf(m, __shfl_xor(m, d));
  if ((threadIdx.x & 63) == 0)
    parts[blockIdx.x * 4 + (threadIdx.x >> 6)] = m;
}

// --------------------------- fused prep ------------------------------------
// 256 threads; block-wide max of parts[1344] (used by bn & w paths).
__device__ __forceinline__ float reduce_parts(const float* __restrict__ parts,
                                              float* lds4) {
  float m = 0.f;
  for (int i = (int)threadIdx.x; i < 1344; i += 256) m = fmaxf(m, parts[i]);
#pragma unroll
  for (int d = 1; d < 64; d <<= 1) m = fmaxf(m, __shfl_xor(m, d));
  if (((int)threadIdx.x & 63) == 0) lds4[(int)threadIdx.x >> 6] = m;
  __syncthreads();
  return fmaxf(fmaxf(lds4[0], lds4[1]), fmaxf(lds4[2], lds4[3]));
}

__global__ void k_fused(const float* __restrict__ X, const float* __restrict__ W,
                        const float* __restrict__ g, const float* __restrict__ be,
                        const float* __restrict__ mn, const float* __restrict__ vr,
                        const float* __restrict__ parts, const int* __restrict__ olen,
                        i8* __restrict__ Xt, i8* __restrict__ Wp,
                        float* __restrict__ bnA, float* __restrict__ bnB,
                        u32* __restrict__ feat) {
  __shared__ float smem[C_SZ * 65];           // xt tile / reduce scratch
  const int tid = (int)threadIdx.x;
  const int bid = (int)blockIdx.x;

  if (bid < 4096) {
    // ---- X -> i8 transposed [b][t][ci], fixed scale SX ----
    const int b = bid >> 7;
    const int t0 = (bid & 127) * 64;
    // rows beyond L1+278 are never staged by any surviving conv block
    const int L1 = olen[b] - (KW - 1);
    if (t0 > L1 + 278) return;
    const float* Xb = X + (size_t)b * C_SZ * T_SZ;
    {
      const int cw = tid >> 4;                // 0..15
      const int ch = tid & 15;                // float4 chunk along t
#pragma unroll
      for (int it = 0; it < 8; ++it) {
        const int ci = it * 16 + cw;
        const f32x4 v = *(const f32x4*)&Xb[(size_t)ci * T_SZ + t0 + ch * 4];
        smem[ci * 65 + ch * 4 + 0] = v.x;
        smem[ci * 65 + ch * 4 + 1] = v.y;
        smem[ci * 65 + ch * 4 + 2] = v.z;
        smem[ci * 65 + ch * 4 + 3] = v.w;
      }
    }
    __syncthreads();
    const int t = tid >> 2;                   // 0..63
    const int q = tid & 3;                    // 32-ci quarter
    u32 dw[8];
#pragma unroll
    for (int d = 0; d < 8; ++d) {
      u32 w = 0;
#pragma unroll
      for (int jb = 0; jb < 4; ++jb) {
        const int j = d * 4 + jb;
        const float v = smem[(q * 32 + j) * 65 + t] * SX;
        w |= ((u32)(unsigned char)q8(v)) << (jb * 8);
      }
      dw[d] = w;
    }
    u32* dst = (u32*)(Xt + ((size_t)(b * T_SZ + t0 + t)) * C_SZ + q * 32);
    *(i32x4*)(dst + 0) = (i32x4){(int)dw[0], (int)dw[1], (int)dw[2], (int)dw[3]};
    *(i32x4*)(dst + 4) = (i32x4){(int)dw[4], (int)dw[5], (int)dw[6], (int)dw[7]};
  } else if (bid == 4096) {
    // ---- BN fold (+ dequant scale) and feat zeroing ----
    const float wmax = reduce_parts(parts, smem);
    if (tid < C_SZ) {
      const float sw = 127.f / wmax;
      const float invS = 1.f / (SX * sw);
      float inv = rsqrtf(vr[tid] + 1e-5f);
      float a = g[tid] * inv;
      bnA[tid] = a * invS;
      bnB[tid] = be[tid] - a * mn[tid];
    }
    for (int i = tid; i < B_SZ * FEAT; i += 256) feat[i] = 0u;
  } else {
    // ---- W -> i8 wave panels ----
    // Wp byte idx = (((k*2+wr)*8 + f)*64 + lane)*16 + e   (f = ks*4 + m)
    // maps W[co = wr*64+m*16+(lane&15)][ci = ks*64+(lane>>4)*16+e][k]
    const float wmax = reduce_parts(parts, smem);
    const float sw = 127.f / wmax;
    const int i = (bid - 4097) * 256 + tid;   // 1344 blocks -> 344064
    const int e = i & 15;
    const int lane = (i >> 4) & 63;
    const int f = (i >> 10) & 7;
    const int wr = (i >> 13) & 1;
    const int k = i >> 14;
    const int m = f & 3, ks = f >> 2;
    const int co = wr * 64 + m * 16 + (lane & 15);
    const int ci = ks * 64 + (lane >> 4) * 16 + e;
    Wp[i] = q8(W[(co * C_SZ + ci) * KW + k] * sw);
  }
}

// --------------------------- conv + SPP-max (int domain) -------------------
// Block 256 thr (4 waves 2x2), tile 128co x 256t; wave 64co x 128t.
// Early-exit: t0 >= L1 -> entire tile dead. Barrier-free K-loop with
// WAVE-STAGGERED tap order: wave wid walks taps (5*wid + kk) mod 21 so
// co-resident waves' stalls interleave (i32 tap sum commutes -> exact).
// av in registers (L2 panels, ks-half rotation); bv from granule-XOR
// swizzled i8 Xs. Epilogue: window max in raw i32; 4 windows, 2 derived.
__global__ __launch_bounds__(256, 2)
void k_conv(const i8* __restrict__ Xt, const i8* __restrict__ Wp,
            const float* __restrict__ bnA, const float* __restrict__ bnB,
            const int* __restrict__ olen, u32* __restrict__ feat) {
  __shared__ __align__(16) i8 Xs[280 * C_SZ];   // 35840 B
  __shared__ int parti[2][4][C_SZ];             //  4096 B (total 39936)

  const int tid = (int)threadIdx.x;
  const int wid = tid >> 6, lane = tid & 63;
  const int wr = wid >> 1, wc = wid & 1;
  const int l4 = lane & 15, lh = lane >> 4;
  const int b = (int)blockIdx.y;
  const int t0 = (int)blockIdx.x * 256;

  const int len = olen[b];
  const int L1 = len - (KW - 1);
  const int L2 = len - 2 * (KW - 1);
  if (t0 >= L1) return;                       // dead tile: no window reaches it

  const int kstart = wid * 5;                 // per-wave tap rotation

  // ---- prefetch W panels for the wave's FIRST tap (kstart) ----
  const i8* wbase = Wp + ((size_t)wr << 13) + (lane << 4);
  i32x4 av[2][4];
#pragma unroll
  for (int f = 0; f < 8; ++f)
    av[f >> 2][f & 3] = *(const i32x4*)&wbase[((size_t)kstart << 14) + (f << 10)];

  // ---- stage Xs rows 0..279 (8 rows = 1024B per wave-instruction) ----
  // LDS[row][g] = global[row][g ^ (row&7)] (16B granules)
  {
    const i8* xb = Xt + (size_t)b * T_SZ * C_SZ;
    for (int i = wid; i < 35; i += 4) {
      int trow = t0 + i * 8 + (lane >> 3);
      trow = trow < T_SZ ? trow : (T_SZ - 1);
      const i8* src = xb + (size_t)trow * C_SZ + (((lane & 7) ^ (trow & 7)) << 4);
      gload_lds16(&Xs[i * 1024], src);
    }
  }
  __syncthreads();                            // the only barrier before epilogue

  i32x4 acc[4][8];
#pragma unroll
  for (int m = 0; m < 4; ++m)
#pragma unroll
    for (int n = 0; n < 8; ++n) acc[m][n] = (i32x4){0, 0, 0, 0};

  const int rowc = wc * 128 + l4;
#pragma unroll 3
  for (int kk = 0; kk < KW; ++kk) {
    int k = kstart + kk;  k  = (k  >= KW) ? k  - KW : k;   // this wave's tap
    int kn = k + 1;       kn = (kn >= KW) ? 0       : kn;  // next in rotation
    if (kk == KW - 1) kn = k;                 // last: re-load self (discarded)
    const int rowb = rowc + k;
    const i8* wbn = wbase + ((size_t)kn << 14);
#pragma unroll
    for (int ks = 0; ks < 2; ++ks) {
      const int gran = ((ks << 2) + lh) ^ (rowb & 7);
      const i8* xp = &Xs[(rowb << 7) + (gran << 4)];
      i32x4 bv[8];
#pragma unroll
      for (int n = 0; n < 8; ++n)
        bv[n] = *(const i32x4*)&xp[n << 11];  // n*16 rows * 128B
      __builtin_amdgcn_s_setprio(1);
#pragma unroll
      for (int m = 0; m < 4; ++m)
#pragma unroll
        for (int n = 0; n < 8; ++n)
          acc[m][n] = __builtin_amdgcn_mfma_i32_16x16x64_i8(
              av[ks][m], bv[n], acc[m][n], 0, 0, 0);
      __builtin_amdgcn_s_setprio(0);
      // prefetch this ks-half of the wave's next tap (~32 MFMA distance)
#pragma unroll
      for (int m = 0; m < 4; ++m)
        av[ks][m] = *(const i32x4*)&wbn[((ks << 2) + m) << 10];
    }
  }

  // ---- epilogue: 4-window ragged max in i32 domain ----
  int wlo[4], whi[4];
  wlo[0] = 0;       whi[0] = (L1 + 1) >> 1;   // w1
  wlo[1] = L1 >> 1; whi[1] = L1;              // w2
  wlo[2] = 0;       whi[2] = (L2 + 1) >> 1;   // w4
  wlo[3] = L2 >> 1; whi[3] = L2;              // w5

  int tg[8];
#pragma unroll
  for (int n = 0; n < 8; ++n) tg[n] = t0 + wc * 128 + n * 16 + l4;

#pragma unroll
  for (int w = 0; w < 4; ++w) {
    bool pr[8];
#pragma unroll
    for (int n = 0; n < 8; ++n) pr[n] = (tg[n] >= wlo[w]) & (tg[n] < whi[w]);
#pragma unroll
    for (int m = 0; m < 4; ++m)
#pragma unroll
      for (int r = 0; r < 4; ++r) {
        int mx = IMIN;
#pragma unroll
        for (int n = 0; n < 8; ++n)
          mx = max(mx, pr[n] ? acc[m][n][r] : IMIN);
#pragma unroll
        for (int d = 1; d < 16; d <<= 1) mx = max(mx, __shfl_xor(mx, d));
        if (l4 == 0) parti[wc][w][wr * 64 + m * 16 + lh * 4 + r] = mx;
      }
  }
  __syncthreads();
  // ---- combine: BN + leaky + fkey on 6x128 reduced values ----
  if (tid < C_SZ) {
    const int c = tid;
    const int v1 = max(parti[0][0][c], parti[1][0][c]);
    const int v2 = max(parti[0][1][c], parti[1][1][c]);
    const int v4 = max(parti[0][2][c], parti[1][2][c]);
    const int v5 = max(parti[0][3][c], parti[1][3][c]);
    const int v0 = max(v1, v2);
    const int v3 = max(v4, v5);
    const float a = bnA[c], bb = bnB[c];
    u32* fb_ = feat + b * FEAT;
    float h;
    h = a * (float)v0 + bb; h = h > 0.f ? h : 0.01f * h;
    atomicMax(&fb_[c], fkey(h));
    h = a * (float)v1 + bb; h = h > 0.f ? h : 0.01f * h;
    atomicMax(&fb_[128 + 2 * c], fkey(h));
    h = a * (float)v2 + bb; h = h > 0.f ? h : 0.01f * h;
    atomicMax(&fb_[129 + 2 * c], fkey(h));
    h = a * (float)v3 + bb; h = h > 0.f ? h : 0.01f * h;
    atomicMax(&fb_[384 + c], fkey(h));
    h = a * (float)v4 + bb; h = h > 0.f ? h : 0.01f * h;
    atomicMax(&fb_[512 + 2 * c], fkey(h));
    h = a * (float)v5 + bb; h = h > 0.f ? h : 0.01f * h;
    atomicMax(&fb_[513 + 2 * c], fkey(h));
  }
}

// --------------------------- FC head ---------------------------------------
__global__ void k_fc(const u32* __restrict__ feat, const float* __restrict__ fw,
                     const float* __restrict__ fb, float* __restrict__ out) {
  const int bj = (int)blockIdx.x;             // 0..63
  const int b = bj >> 1, j = bj & 1;
  const int lane = (int)threadIdx.x;          // 64
  float s = 0.f;
  for (int i = lane; i < FEAT; i += 64)
    s += funkey(feat[b * FEAT + i]) * fw[j * FEAT + i];
#pragma unroll
  for (int d = 1; d < 64; d <<= 1) s += __shfl_xor(s, d);
  if (lane == 0) out[b * 2 + j] = s + fb[j];
}

// ---------------------------------------------------------------------------
extern "C" void kernel_launch(void* const* d_in, const int* in_sizes, int n_in,
                              void* d_out, int out_size, void* d_ws, size_t ws_size,
                              hipStream_t stream) {
  (void)in_sizes; (void)n_in; (void)out_size; (void)ws_size;
  const float* x     = (const float*)d_in[0];
  const int*   olen  = (const int*)d_in[1];
  const float* w     = (const float*)d_in[2];
  const float* gamma = (const float*)d_in[3];
  const float* beta  = (const float*)d_in[4];
  const float* mean  = (const float*)d_in[5];
  const float* var   = (const float*)d_in[6];
  const float* fw    = (const float*)d_in[7];
  const float* fb    = (const float*)d_in[8];
  float* out = (float*)d_out;

  char* ws = (char*)d_ws;
  i8*  Xt    = (i8*)(ws + XT_OFF);
  i8*  Wp    = (i8*)(ws + WP_OFF);
  float* bnA  = (float*)(ws + BNA_OFF);
  float* bnB  = (float*)(ws + BNB_OFF);
  u32* feat  = (u32*)(ws + FK_OFF);
  float* parts = (float*)(ws + PT_OFF);

  k_absmax<<<336, 256, 0, stream>>>(w, parts);
  k_fused<<<4097 + 1344, 256, 0, stream>>>(x, w, gamma, beta, mean, var, parts,
                                           olen, Xt, Wp, bnA, bnB, feat);
  k_conv<<<dim3(T_SZ / 256, B_SZ), 256, 0, stream>>>(Xt, Wp, bnA, bnB, olen, feat);
  k_fc<<<64, 64, 0, stream>>>(feat, fw, fb, out);
}

// Round 14
// 99.119 us; speedup vs baseline: 1.0639x; 1.0639x over previous
//
#include <hip/hip_runtime.h>

// ---------------------------------------------------------------------------
// SPP_CNN: conv1d(128->128,K=21,VALID) + BN(eval) + LeakyReLU(0.01)
//          + 2x ragged SPP-max (levels 1,2) + FC(768->2)
// R14 = R13 with k_conv re-granularized: 128-thread blocks (2 waves, tile
// 128co x 128t; wave = the proven 64co x 128t inner loop, unchanged) running
// a persistent WORKLIST of live (b, t-tile) items built by k_fused.
// 4 blocks/CU (vs 2) -> 4 independent streams to overlap LDS/L2/MFMA pipes;
// items/slots ~1.13 -> tail is 2 small items, not 2 big rounds.
// av registers persist across items (same W; last tap prefetches tap 0).
// Invariants (R3/R8/R10): wave 64co x 128t, av 8KB/tap/wave, 64-MFMA
// prefetch distance. Math bit-identical to R12/R13.
// Pipeline: 4 dispatches (absmax -> fused prep -> conv -> fc).
// Workspace layout:
//   Xt   : i8  [32][8192][128]  (x transposed, quantized)     @ 0
//   Wp   : i8  [21][2][8][64][16] ([k][wr][f=ks*4+m][lane][e])@ 33554432
//   bnA  : f32 [128] (gamma*inv/(sx*sw))                      @ 33898496
//   bnB  : f32 [128]                                          @ 33899008
//   feat : u32 [32][768]  (monotonic float keys)              @ 33899520
//   parts: f32 [1344]     (absmax per-wave partials)          @ 33997824
//   wl   : u32 [1+2048]   (worklist: count, then (b<<16)|tile)@ 34003200
// ---------------------------------------------------------------------------

typedef __attribute__((ext_vector_type(4))) float f32x4;
typedef __attribute__((ext_vector_type(4))) int i32x4;
typedef unsigned short u16;
typedef unsigned int u32;
typedef signed char i8;

#define T_SZ 8192
#define C_SZ 128
#define B_SZ 32
#define KW 21
#define FEAT 768
#define SX 25.4f              /* 127/5: x ~ N(0,1), clip at 5 sigma */
#define IMIN (-2147483647 - 1)

#define XT_OFF  0
#define WP_OFF  33554432u
#define BNA_OFF 33898496u
#define BNB_OFF 33899008u
#define FK_OFF  33899520u
#define PT_OFF  33997824u
#define WL_OFF  34003200u

__device__ __forceinline__ u32 fkey(float f) {          // order-preserving
  u32 u = __float_as_uint(f);
  return (u & 0x80000000u) ? ~u : (u | 0x80000000u);
}
__device__ __forceinline__ float funkey(u32 k) {
  u32 u = (k & 0x80000000u) ? (k ^ 0x80000000u) : ~k;
  return __uint_as_float(u);
}

__device__ __forceinline__ i8 q8(float v) {
  v = fminf(fmaxf(v, -127.f), 127.f);
  return (i8)__float2int_rn(v);
}

__device__ __forceinline__ void gload_lds16(void* lds, const void* g) {
  __builtin_amdgcn_global_load_lds(
      (const __attribute__((address_space(1))) u32*)g,
      (__attribute__((address_space(3))) u32*)lds, 16, 0, 0);
}

// --------------------------- prep: |W| absmax partials ---------------------
__global__ void k_absmax(const float* __restrict__ W, float* __restrict__ parts) {
  const int i0 = ((int)blockIdx.x * 256 + (int)threadIdx.x) * 4;  // 336 blocks
  float m = 0.f;
#pragma unroll
  for (int j = 0; j < 4; ++j) m = fmaxf(m, fabsf(W[i0 + j]));
#pragma unroll
  for (int d = 1; d < 64; d <<= 1) m = fmaxf(m, __shfl_xor(m, d));
  if ((threadIdx.x & 63) == 0)
    parts[blockIdx.x * 4 + (threadIdx.x >> 6)] = m;
}

// --------------------------- fused prep ------------------------------------
// 256 threads; block-wide max of parts[1344] (used by bn & w paths).
__device__ __forceinline__ float reduce_parts(const float* __restrict__ parts,
                                              float* lds4) {
  float m = 0.f;
  for (int i = (int)threadIdx.x; i < 1344; i += 256) m = fmaxf(m, parts[i]);
#pragma unroll
  for (int d = 1; d < 64; d <<= 1) m = fmaxf(m, __shfl_xor(m, d));
  if (((int)threadIdx.x & 63) == 0) lds4[(int)threadIdx.x >> 6] = m;
  __syncthreads();
  return fmaxf(fmaxf(lds4[0], lds4[1]), fmaxf(lds4[2], lds4[3]));
}

__global__ void k_fused(const float* __restrict__ X, const float* __restrict__ W,
                        const float* __restrict__ g, const float* __restrict__ be,
                        const float* __restrict__ mn, const float* __restrict__ vr,
                        const float* __restrict__ parts, const int* __restrict__ olen,
                        i8* __restrict__ Xt, i8* __restrict__ Wp,
                        float* __restrict__ bnA, float* __restrict__ bnB,
                        u32* __restrict__ feat, u32* __restrict__ wl) {
  __shared__ float smem[C_SZ * 65];           // xt tile / reduce scratch
  const int tid = (int)threadIdx.x;
  const int bid = (int)blockIdx.x;

  if (bid < 4096) {
    // ---- X -> i8 transposed [b][t][ci], fixed scale SX ----
    const int b = bid >> 7;
    const int t0 = (bid & 127) * 64;
    // max row read by any live conv item is L1+150 (t0<=L1-1, +151 rows)
    const int L1 = olen[b] - (KW - 1);
    if (t0 > L1 + 152) return;
    const float* Xb = X + (size_t)b * C_SZ * T_SZ;
    {
      const int cw = tid >> 4;                // 0..15
      const int ch = tid & 15;                // float4 chunk along t
#pragma unroll
      for (int it = 0; it < 8; ++it) {
        const int ci = it * 16 + cw;
        const f32x4 v = *(const f32x4*)&Xb[(size_t)ci * T_SZ + t0 + ch * 4];
        smem[ci * 65 + ch * 4 + 0] = v.x;
        smem[ci * 65 + ch * 4 + 1] = v.y;
        smem[ci * 65 + ch * 4 + 2] = v.z;
        smem[ci * 65 + ch * 4 + 3] = v.w;
      }
    }
    __syncthreads();
    const int t = tid >> 2;                   // 0..63
    const int q = tid & 3;                    // 32-ci quarter
    u32 dw[8];
#pragma unroll
    for (int d = 0; d < 8; ++d) {
      u32 w = 0;
#pragma unroll
      for (int jb = 0; jb < 4; ++jb) {
        const int j = d * 4 + jb;
        const float v = smem[(q * 32 + j) * 65 + t] * SX;
        w |= ((u32)(unsigned char)q8(v)) << (jb * 8);
      }
      dw[d] = w;
    }
    u32* dst = (u32*)(Xt + ((size_t)(b * T_SZ + t0 + t)) * C_SZ + q * 32);
    *(i32x4*)(dst + 0) = (i32x4){(int)dw[0], (int)dw[1], (int)dw[2], (int)dw[3]};
    *(i32x4*)(dst + 4) = (i32x4){(int)dw[4], (int)dw[5], (int)dw[6], (int)dw[7]};
  } else if (bid == 4096) {
    // ---- BN fold (+ dequant scale), feat zeroing, worklist build ----
    const float wmax = reduce_parts(parts, smem);
    if (tid < C_SZ) {
      const float sw = 127.f / wmax;
      const float invS = 1.f / (SX * sw);
      float inv = rsqrtf(vr[tid] + 1e-5f);
      float a = g[tid] * inv;
      bnA[tid] = a * invS;
      bnB[tid] = be[tid] - a * mn[tid];
    }
    for (int i = tid; i < B_SZ * FEAT; i += 256) feat[i] = 0u;
    // worklist: items (b<<16)|tile for tile in [0, ceil(L1/128))
    __shared__ int off[B_SZ + 1];
    if (tid == 0) {
      int s = 0;
      for (int b2 = 0; b2 < B_SZ; ++b2) {
        off[b2] = s;
        s += (olen[b2] - (KW - 1) + 127) >> 7;
      }
      off[B_SZ] = s;
      wl[0] = (u32)s;
    }
    __syncthreads();
    for (int b2 = 0; b2 < B_SZ; ++b2) {
      const int n = off[b2 + 1] - off[b2];
      for (int i = tid; i < n; i += 256)
        wl[1 + off[b2] + i] = ((u32)b2 << 16) | (u32)i;
    }
  } else {
    // ---- W -> i8 wave panels ----
    // Wp byte idx = (((k*2+wr)*8 + f)*64 + lane)*16 + e   (f = ks*4 + m)
    // maps W[co = wr*64+m*16+(lane&15)][ci = ks*64+(lane>>4)*16+e][k]
    const float wmax = reduce_parts(parts, smem);
    const float sw = 127.f / wmax;
    const int i = (bid - 4097) * 256 + tid;   // 1344 blocks -> 344064
    const int e = i & 15;
    const int lane = (i >> 4) & 63;
    const int f = (i >> 10) & 7;
    const int wr = (i >> 13) & 1;
    const int k = i >> 14;
    const int m = f & 3, ks = f >> 2;
    const int co = wr * 64 + m * 16 + (lane & 15);
    const int ci = ks * 64 + (lane >> 4) * 16 + e;
    Wp[i] = q8(W[(co * C_SZ + ci) * KW + k] * sw);
  }
}

// --------------------------- conv + SPP-max (int domain) -------------------
// 1024 persistent blocks of 128 thr (2 waves, wr = co-half). Each block
// strides the worklist of live (b, 128-t-tile) items. Wave = 64co x 128t,
// inner loop identical to R13 (barrier-free taps, av register rotation,
// granule-XOR swizzled Xs, i32-domain monotone epilogue, 4 windows).
// av persists across items: last tap prefetches tap 0 for the next item.
__global__ __launch_bounds__(128, 2)
void k_conv(const i8* __restrict__ Xt, const i8* __restrict__ Wp,
            const float* __restrict__ bnA, const float* __restrict__ bnB,
            const int* __restrict__ olen, const u32* __restrict__ wl,
            u32* __restrict__ feat) {
  __shared__ __align__(16) i8 Xs[152 * C_SZ];   // 19456 B
  __shared__ int parti[4][C_SZ];                //  2048 B (total 21504)

  const int tid = (int)threadIdx.x;
  const int wr = tid >> 6, lane = tid & 63;
  const int l4 = lane & 15, lh = lane >> 4;
  const int bid = (int)blockIdx.x;

  // ---- av panels for tap 0 (reused across items; same W for all items) ----
  const i8* wbase = Wp + ((size_t)wr << 13) + (lane << 4);
  i32x4 av[2][4];
#pragma unroll
  for (int f = 0; f < 8; ++f)
    av[f >> 2][f & 3] = *(const i32x4*)&wbase[f << 10];

  const int nit = (int)wl[0];
  for (int it = bid; it < nit; it += 1024) {
    const u32 e = wl[1 + it];
    const int b = (int)(e >> 16);
    const int t0 = (int)(e & 0xffffu) << 7;
    const int len = olen[b];
    const int L1 = len - (KW - 1);
    const int L2 = len - 2 * (KW - 1);

    // ---- stage Xs rows t0..t0+151 (8 rows = 1024B per wave-instruction) ----
    // LDS[row][g] = global[row][g ^ (row&7)] (16B granules)
    {
      const i8* xb = Xt + (size_t)b * T_SZ * C_SZ;
      for (int i = wr; i < 19; i += 2) {
        int trow = t0 + i * 8 + (lane >> 3);
        trow = trow < T_SZ ? trow : (T_SZ - 1);
        const i8* src = xb + (size_t)trow * C_SZ + (((lane & 7) ^ (trow & 7)) << 4);
        gload_lds16(&Xs[i * 1024], src);
      }
    }
    __syncthreads();                          // staging done (drains vmcnt)

    i32x4 acc[4][8];
#pragma unroll
    for (int m = 0; m < 4; ++m)
#pragma unroll
      for (int n = 0; n < 8; ++n) acc[m][n] = (i32x4){0, 0, 0, 0};

#pragma unroll 3
    for (int k = 0; k < KW; ++k) {
      const int kn = (k + 1 < KW) ? (k + 1) : 0;   // wrap: tap 0 of next item
      const int rowb = l4 + k;
      const i8* wbn = wbase + ((size_t)kn << 14);
#pragma unroll
      for (int ks = 0; ks < 2; ++ks) {
        const int gran = ((ks << 2) + lh) ^ (rowb & 7);
        const i8* xp = &Xs[(rowb << 7) + (gran << 4)];
        i32x4 bv[8];
#pragma unroll
        for (int n = 0; n < 8; ++n)
          bv[n] = *(const i32x4*)&xp[n << 11]; // n*16 rows * 128B
        __builtin_amdgcn_s_setprio(1);
#pragma unroll
        for (int m = 0; m < 4; ++m)
#pragma unroll
          for (int n = 0; n < 8; ++n)
            acc[m][n] = __builtin_amdgcn_mfma_i32_16x16x64_i8(
                av[ks][m], bv[n], acc[m][n], 0, 0, 0);
        __builtin_amdgcn_s_setprio(0);
        // prefetch this ks-half of next tap (~32 MFMA min distance)
#pragma unroll
        for (int m = 0; m < 4; ++m)
          av[ks][m] = *(const i32x4*)&wbn[((ks << 2) + m) << 10];
      }
    }

    // ---- epilogue: 4-window ragged max in i32 domain ----
    int wlo[4], whi[4];
    wlo[0] = 0;       whi[0] = (L1 + 1) >> 1;   // w1
    wlo[1] = L1 >> 1; whi[1] = L1;              // w2
    wlo[2] = 0;       whi[2] = (L2 + 1) >> 1;   // w4
    wlo[3] = L2 >> 1; whi[3] = L2;              // w5

    int tg[8];
#pragma unroll
    for (int n = 0; n < 8; ++n) tg[n] = t0 + n * 16 + l4;

#pragma unroll
    for (int w = 0; w < 4; ++w) {
      bool pr[8];
#pragma unroll
      for (int n = 0; n < 8; ++n) pr[n] = (tg[n] >= wlo[w]) & (tg[n] < whi[w]);
#pragma unroll
      for (int m = 0; m < 4; ++m)
#pragma unroll
        for (int r = 0; r < 4; ++r) {
          int mx = IMIN;
#pragma unroll
          for (int n = 0; n < 8; ++n)
            mx = max(mx, pr[n] ? acc[m][n][r] : IMIN);
#pragma unroll
          for (int d = 1; d < 16; d <<= 1) mx = max(mx, __shfl_xor(mx, d));
          if (l4 == 0) parti[w][wr * 64 + m * 16 + lh * 4 + r] = mx;
        }
    }
    __syncthreads();                          // K-loop LDS reads + parti done
    // ---- combine: BN + leaky + fkey on 6x128 reduced values ----
    {
      const int c = tid;                      // 128 threads = 128 channels
      const int v1 = parti[0][c];
      const int v2 = parti[1][c];
      const int v4 = parti[2][c];
      const int v5 = parti[3][c];
      const int v0 = max(v1, v2);
      const int v3 = max(v4, v5);
      const float a = bnA[c], bb = bnB[c];
      u32* fb_ = feat + b * FEAT;
      float h;
      h = a * (float)v0 + bb; h = h > 0.f ? h : 0.01f * h;
      atomicMax(&fb_[c], fkey(h));
      h = a * (float)v1 + bb; h = h > 0.f ? h : 0.01f * h;
      atomicMax(&fb_[128 + 2 * c], fkey(h));
      h = a * (float)v2 + bb; h = h > 0.f ? h : 0.01f * h;
      atomicMax(&fb_[129 + 2 * c], fkey(h));
      h = a * (float)v3 + bb; h = h > 0.f ? h : 0.01f * h;
      atomicMax(&fb_[384 + c], fkey(h));
      h = a * (float)v4 + bb; h = h > 0.f ? h : 0.01f * h;
      atomicMax(&fb_[512 + 2 * c], fkey(h));
      h = a * (float)v5 + bb; h = h > 0.f ? h : 0.01f * h;
      atomicMax(&fb_[513 + 2 * c], fkey(h));
    }
    // next item's staging overwrites Xs only after the barrier above; its
    // writes target Xs while combine reads parti (disjoint) -> safe.
  }
}

// --------------------------- FC head ---------------------------------------
__global__ void k_fc(const u32* __restrict__ feat, const float* __restrict__ fw,
                     const float* __restrict__ fb, float* __restrict__ out) {
  const int bj = (int)blockIdx.x;             // 0..63
  const int b = bj >> 1, j = bj & 1;
  const int lane = (int)threadIdx.x;          // 64
  float s = 0.f;
  for (int i = lane; i < FEAT; i += 64)
    s += funkey(feat[b * FEAT + i]) * fw[j * FEAT + i];
#pragma unroll
  for (int d = 1; d < 64; d <<= 1) s += __shfl_xor(s, d);
  if (lane == 0) out[b * 2 + j] = s + fb[j];
}

// ---------------------------------------------------------------------------
extern "C" void kernel_launch(void* const* d_in, const int* in_sizes, int n_in,
                              void* d_out, int out_size, void* d_ws, size_t ws_size,
                              hipStream_t stream) {
  (void)in_sizes; (void)n_in; (void)out_size; (void)ws_size;
  const float* x     = (const float*)d_in[0];
  const int*   olen  = (const int*)d_in[1];
  const float* w     = (const float*)d_in[2];
  const float* gamma = (const float*)d_in[3];
  const float* beta  = (const float*)d_in[4];
  const float* mean  = (const float*)d_in[5];
  const float* var   = (const float*)d_in[6];
  const float* fw    = (const float*)d_in[7];
  const float* fb    = (const float*)d_in[8];
  float* out = (float*)d_out;

  char* ws = (char*)d_ws;
  i8*  Xt    = (i8*)(ws + XT_OFF);
  i8*  Wp    = (i8*)(ws + WP_OFF);
  float* bnA  = (float*)(ws + BNA_OFF);
  float* bnB  = (float*)(ws + BNB_OFF);
  u32* feat  = (u32*)(ws + FK_OFF);
  float* parts = (float*)(ws + PT_OFF);
  u32* wl    = (u32*)(ws + WL_OFF);

  k_absmax<<<336, 256, 0, stream>>>(w, parts);
  k_fused<<<4097 + 1344, 256, 0, stream>>>(x, w, gamma, beta, mean, var, parts,
                                           olen, Xt, Wp, bnA, bnB, feat, wl);
  k_conv<<<1024, 128, 0, stream>>>(Xt, Wp, bnA, bnB, olen, wl, feat);
  k_fc<<<64, 64, 0, stream>>>(feat, fw, fb, out);
}